// Round 12
// baseline (544.236 us; speedup 1.0000x reference)
//
#include <hip/hip_runtime.h>
#include <math.h>

#define N_NODES 100000
#define M_PAD 100096  /* 782*128 */
#define NFEAT 512
#define NHID 256
#define NCLASS 40
#define SUP2_LD 48   /* padded cols for MFMA gemm2 */

#define NBKT 250       /* coarse buckets */
#define NPB 400        /* nodes per bucket: 250*400 = 100000 exactly */
#define BINA_CHUNK 3072 /* 24KB sorted + 3KB bkt8 + 4KB scan = 31.7KB < gemm1's 48KB */
#define BCAP 14336     /* fixed bucket capacity (avg 12800, sigma~113) */

#define GEMM1_TILES 782      /* M_PAD/128 */
#define GEMM1_BLOCKS 391     /* 2 tiles per block: all co-resident at 3 blocks/CU */

typedef __attribute__((ext_vector_type(8))) short bf16x8;
typedef __attribute__((ext_vector_type(4))) float f32x4;

__device__ __forceinline__ unsigned short f2bf(float f) {
    unsigned int u = __builtin_bit_cast(unsigned int, f);
    u += 0x7fffu + ((u >> 16) & 1u);  // RNE
    return (unsigned short)(u >> 16);
}
__device__ __forceinline__ void bf2x2(unsigned int u, float& f0, float& f1) {
    f0 = __builtin_bit_cast(float, u << 16);
    f1 = __builtin_bit_cast(float, u & 0xffff0000u);
}
__device__ __forceinline__ void gload16(const void* g, void* l) {
    __builtin_amdgcn_global_load_lds(
        (const __attribute__((address_space(1))) unsigned int*)g,
        (__attribute__((address_space(3))) unsigned int*)l, 16, 0, 0);
}
// conflict-free crossbar xor-swizzle within 32-lane groups (BitMode)
template <int CODE>
__device__ __forceinline__ float swzx(float v) {
    return __builtin_bit_cast(float,
        __builtin_amdgcn_ds_swizzle(__builtin_bit_cast(int, v), CODE));
}

// ---------------- init: bcur bases + w1t transpose + w2 frag-pack ----------------
#define CVTW_BLOCKS 512   /* 256*512/256 */

__global__ __launch_bounds__(256) void k_init(int* __restrict__ bcur,
                                              const float* __restrict__ W1,
                                              unsigned short* __restrict__ w1t,
                                              const float* __restrict__ W2,
                                              uint4* __restrict__ w2f) {
    int b = blockIdx.x;
    int t = threadIdx.x;
    if (b == 0) {
        if (t < NBKT) bcur[t] = t * BCAP;
    } else if (b <= CVTW_BLOCKS) {
        // W1 [512][256] -> w1t [256][512] transposed bf16
        int idx = (b - 1) * 256 + t;
        int n = idx >> 9, k = idx & 511;
        w1t[idx] = f2bf(W1[(size_t)k * NHID + n]);
    } else {
        // W2 [256][40] f32 -> frag-packed bf16 w2f[ks][n][lane] (8*3*64 frags of 16B)
        for (int idx = t; idx < 8 * 3 * 64; idx += 256) {
            int ks = idx / 192;
            int rem = idx - ks * 192;
            int n = rem >> 6;
            int l = rem & 63;
            int col = n * 16 + (l & 15);
            int kbase = ks * 32 + (l >> 4) * 8;
            unsigned short o[8];
#pragma unroll
            for (int j = 0; j < 8; ++j)
                o[j] = (col < NCLASS) ? f2bf(W2[(size_t)(kbase + j) * NCLASS + col]) : 0;
            w2f[idx] = *(const uint4*)o;
        }
    }
}

// ---------------- binA body: LDS counting-sort chunk into 250 buckets ----------------
__device__ __forceinline__ void binA_body(char* smbase, int t, int cblk,
                                          const int* __restrict__ src,
                                          const int* __restrict__ dst,
                                          const float* __restrict__ ew,
                                          int* __restrict__ bcur,
                                          uint2* __restrict__ tmp, int E) {
    uint2* sorted = (uint2*)smbase;                          // 24576 B
    unsigned char* bkt8 = (unsigned char*)(smbase + 24576);  // 3072 B
    int* cnt = (int*)(smbase + 27648);
    int* startv = cnt + 256;
    int* offv = startv + 256;
    int* gb = offv + 256;
    int c0 = cblk * BINA_CHUNK;
    int n = min(BINA_CHUNK, E - c0);
    cnt[t] = 0;
    __syncthreads();
    // pass 1: per-bucket count
    for (int j = t; j < n; j += 256) {
        atomicAdd(&cnt[(unsigned)dst[c0 + j] / NPB], 1);
    }
    __syncthreads();
    int v = cnt[t];
    startv[t] = v;
    __syncthreads();
    for (int o = 1; o < 256; o <<= 1) {
        int a = (t >= o) ? startv[t - o] : 0;
        __syncthreads();
        startv[t] += a;
        __syncthreads();
    }
    int ex = startv[t] - v;  // exclusive start
    __syncthreads();
    startv[t] = ex;
    offv[t] = ex;
    if (t < NBKT) gb[t] = (v > 0) ? atomicAdd(&bcur[t], v) : 0;
    __syncthreads();
    // pass 2: rank + place into LDS (sorted by bucket)
    for (int j = t; j < n; j += 256) {
        int d = dst[c0 + j];
        int b = (unsigned)d / NPB;
        int dl = d - b * NPB;  // < 400, 9 bits
        int r = atomicAdd(&offv[b], 1);
        sorted[r] = make_uint2((unsigned)src[c0 + j] | ((unsigned)dl << 17),
                               __builtin_bit_cast(unsigned, ew[c0 + j]));
        bkt8[r] = (unsigned char)b;
    }
    __syncthreads();
    // drain: linear over sorted -> coalesced bursts per bucket region
    for (int j = t; j < n; j += 256) {
        int b = bkt8[j];
        tmp[gb[b] + (j - startv[b])] = sorted[j];
    }
}

// ---------------- gemm1 body: one 128-row tile of sup1 = bf16(x) @ W1, BK=32 ----------------
__device__ __forceinline__ void gemm1_body(char* smem, int t, int mb,
                                           const float* __restrict__ x,
                                           const unsigned short* __restrict__ w1t,
                                           unsigned short* __restrict__ sup1) {
    const int w = t >> 6, lane = t & 63;
    const int m0 = mb * 128;
    const int wm = w >> 1, wn = w & 1;
    const int r15 = lane & 15, hi = lane >> 4;

    f32x4 acc[4][8];
#pragma unroll
    for (int i = 0; i < 4; ++i)
#pragma unroll
        for (int j = 0; j < 8; ++j) acc[i][j] = (f32x4){0.f, 0.f, 0.f, 0.f};

    const char* wsrc = (const char*)w1t;

#define STAGE1(kt, b)                                                                  \
    {                                                                                  \
        char* Ab = smem + (b) * 8192;                                                  \
        char* Bb = smem + 16384 + (b) * 16384;                                         \
        _Pragma("unroll") for (int i = 0; i < 2; ++i) {                                \
            int u = i * 256 + t;                                                       \
            int row = u >> 2, part = u & 3;                                            \
            int gr = m0 + row;                                                         \
            unsigned short ob[8];                                                      \
            if (gr < N_NODES) {                                                        \
                const float* sp = x + (size_t)gr * NFEAT + (kt) * 32 + part * 8;       \
                float4 v0 = *(const float4*)sp;                                        \
                float4 v1 = *(const float4*)(sp + 4);                                  \
                ob[0] = f2bf(v0.x); ob[1] = f2bf(v0.y);                                \
                ob[2] = f2bf(v0.z); ob[3] = f2bf(v0.w);                                \
                ob[4] = f2bf(v1.x); ob[5] = f2bf(v1.y);                                \
                ob[6] = f2bf(v1.z); ob[7] = f2bf(v1.w);                                \
            } else {                                                                   \
                _Pragma("unroll") for (int j = 0; j < 8; ++j) ob[j] = 0;               \
            }                                                                          \
            *(uint4*)(Ab + row * 64 + ((part ^ ((row >> 1) & 3)) << 4)) =              \
                *(const uint4*)ob;                                                     \
        }                                                                              \
        _Pragma("unroll") for (int i = 0; i < 4; ++i) {                                \
            int u = i * 256 + t;                                                       \
            int nrow = u >> 2, part = u & 3;                                           \
            int q = part ^ ((nrow >> 1) & 3);                                          \
            gload16(wsrc + (size_t)nrow * 1024 + (kt) * 64 + q * 16, Bb + u * 16);     \
        }                                                                              \
    }

    STAGE1(0, 0);
    for (int kt = 0; kt < 16; ++kt) {
        __syncthreads();
        if (kt < 15) STAGE1(kt + 1, (kt + 1) & 1);
        const char* Ab = smem + (kt & 1) * 8192;
        const char* Bb = smem + 16384 + (kt & 1) * 16384;
        bf16x8 a[4], bb[8];
#pragma unroll
        for (int i = 0; i < 4; ++i) {
            int r = wm * 64 + i * 16 + r15;
            a[i] = *(const bf16x8*)(Ab + r * 64 + ((hi ^ ((r >> 1) & 3)) << 4));
        }
#pragma unroll
        for (int j = 0; j < 8; ++j) {
            int n = wn * 128 + j * 16 + r15;
            bb[j] = *(const bf16x8*)(Bb + n * 64 + ((hi ^ ((n >> 1) & 3)) << 4));
        }
#pragma unroll
        for (int i = 0; i < 4; ++i)
#pragma unroll
            for (int j = 0; j < 8; ++j)
                acc[i][j] = __builtin_amdgcn_mfma_f32_16x16x32_bf16(a[i], bb[j], acc[i][j], 0, 0, 0);
    }
#undef STAGE1

#pragma unroll
    for (int i = 0; i < 4; ++i) {
        int rowb = m0 + wm * 64 + i * 16 + hi * 4;
#pragma unroll
        for (int j = 0; j < 8; ++j) {
            int col = wn * 128 + j * 16 + r15;
#pragma unroll
            for (int r = 0; r < 4; ++r)
                sup1[(size_t)(rowb + r) * NHID + col] = f2bf(acc[i][j][r]);
        }
    }
}

// ---------------- fat: gemm1 (391 blocks x 2 tiles) first, binA backfills ----------------
__global__ __launch_bounds__(256) void k_fat(const float* __restrict__ x,
                                             const unsigned short* __restrict__ w1t,
                                             unsigned short* __restrict__ sup1,
                                             const int* __restrict__ src,
                                             const int* __restrict__ dst,
                                             const float* __restrict__ ew,
                                             int* __restrict__ bcur,
                                             uint2* __restrict__ tmp, int E) {
    __shared__ __align__(16) char smem[49152];
    int b = blockIdx.x;
    int t = threadIdx.x;
    if (b < GEMM1_BLOCKS) {
        gemm1_body(smem, t, b, x, w1t, sup1);
        __syncthreads();  // smem reuse across tiles
        gemm1_body(smem, t, b + GEMM1_BLOCKS, x, w1t, sup1);
    } else {
        binA_body(smem, t, b - GEMM1_BLOCKS, src, dst, ew, bcur, tmp, E);
    }
}

// ---------------- binB: bucket-local hist + scan + rowptr write + scatter ----------------
__global__ __launch_bounds__(256) void k_binB(const uint2* __restrict__ tmp,
                                              const int* __restrict__ bcur,
                                              int* __restrict__ rowptr,
                                              uint2* __restrict__ cedge) {
    __shared__ int sc[256];   // scan scratch
    __shared__ int nc[NPB];   // per-node hist
    __shared__ int st[NPB];   // starts -> global cursors
    int b = blockIdx.x, t = threadIdx.x;
    // 1) scan the 250 bucket counts -> my base and count
    int c = (t < NBKT) ? (bcur[t] - t * BCAP) : 0;
    sc[t] = c;
    __syncthreads();
    for (int o = 1; o < 256; o <<= 1) {
        int a = (t >= o) ? sc[t - o] : 0;
        __syncthreads();
        sc[t] += a;
        __syncthreads();
    }
    int base = (b == 0) ? 0 : sc[b - 1];
    int mycnt = sc[b] - base;
    int total = sc[NBKT - 1];
    __syncthreads();
    // 2) LDS histogram of node-local ids
    for (int i = t; i < NPB; i += 256) nc[i] = 0;
    __syncthreads();
    const uint2* srcp = tmp + (size_t)b * BCAP;
    for (int j = t; j < mycnt; j += 256) atomicAdd(&nc[srcp[j].x >> 17], 1);
    __syncthreads();
    // 3) exclusive scan of nc[400] (two 256-chunks)
    int v0 = nc[t];
    sc[t] = v0;
    __syncthreads();
    for (int o = 1; o < 256; o <<= 1) {
        int a = (t >= o) ? sc[t - o] : 0;
        __syncthreads();
        sc[t] += a;
        __syncthreads();
    }
    int tot0 = sc[255];
    st[t] = sc[t] - v0;
    __syncthreads();
    int v1 = (t < NPB - 256) ? nc[256 + t] : 0;
    sc[t] = v1;
    __syncthreads();
    for (int o = 1; o < 256; o <<= 1) {
        int a = (t >= o) ? sc[t - o] : 0;
        __syncthreads();
        sc[t] += a;
        __syncthreads();
    }
    if (t < NPB - 256) st[256 + t] = tot0 + sc[t] - v1;
    __syncthreads();
    // 4) write rowptr slice coalesced; convert st to global cursors
    int n0 = b * NPB;
    for (int i = t; i < NPB; i += 256) {
        int s = base + st[i];
        rowptr[n0 + i] = s;
        st[i] = s;
    }
    if (b == NBKT - 1 && t == 0) rowptr[N_NODES] = total;
    __syncthreads();
    // 5) scatter within block-private window
    for (int j = t; j < mycnt; j += 256) {
        uint2 e = srcp[j];
        int dl = e.x >> 17;
        int addr = atomicAdd(&st[dl], 1);
        cedge[addr] = make_uint2(e.x & 0x1FFFFu, e.y);
    }
}

// ---------------- propagate 1 (bf16 rows, packed edges, 8-unroll) + bias + relu ----------------
__global__ __launch_bounds__(256) void k_prop1(const unsigned short* __restrict__ sup1,
                                               const int* __restrict__ rowptr,
                                               const uint2* __restrict__ cedge,
                                               const float* __restrict__ b1,
                                               unsigned short* __restrict__ h1) {
    int gid = blockIdx.x * blockDim.x + threadIdx.x;
    int wid = gid >> 6;
    int lane = gid & 63;
    if (wid >= N_NODES) return;
    int beg = rowptr[wid], end = rowptr[wid + 1];
    float a0 = 0.f, a1 = 0.f, a2 = 0.f, a3 = 0.f;
    int e = beg;
    for (; e + 7 < end; e += 8) {
        uint2 ed[8];
#pragma unroll
        for (int q = 0; q < 8; ++q) ed[q] = cedge[e + q];
        uint2 r[8];
#pragma unroll
        for (int q = 0; q < 8; ++q)
            r[q] = *(const uint2*)(sup1 + (size_t)ed[q].x * NHID + lane * 4);
#pragma unroll
        for (int q = 0; q < 8; ++q) {
            float wq = __builtin_bit_cast(float, ed[q].y);
            float f0, f1, f2, f3;
            bf2x2(r[q].x, f0, f1);
            bf2x2(r[q].y, f2, f3);
            a0 += wq * f0; a1 += wq * f1; a2 += wq * f2; a3 += wq * f3;
        }
    }
    for (; e < end; ++e) {
        uint2 ed = cedge[e];
        float wq = __builtin_bit_cast(float, ed.y);
        uint2 rv = *(const uint2*)(sup1 + (size_t)ed.x * NHID + lane * 4);
        float f0, f1, f2, f3;
        bf2x2(rv.x, f0, f1);
        bf2x2(rv.y, f2, f3);
        a0 += wq * f0; a1 += wq * f1; a2 += wq * f2; a3 += wq * f3;
    }
    float4 bv = *(const float4*)(b1 + lane * 4);
    a0 = fmaxf(a0 + bv.x, 0.f);
    a1 = fmaxf(a1 + bv.y, 0.f);
    a2 = fmaxf(a2 + bv.z, 0.f);
    a3 = fmaxf(a3 + bv.w, 0.f);
    unsigned short o[4] = {f2bf(a0), f2bf(a1), f2bf(a2), f2bf(a3)};
    *(uint2*)(h1 + (size_t)wid * NHID + lane * 4) = *(const uint2*)o;
}

// ---------------- GEMM2 (MFMA): sup2[M_PAD][48] = h1 @ W2  (W2 frag-packed) ----------------
__global__ __launch_bounds__(256) void k_gemm2(const unsigned short* __restrict__ h1,
                                               const uint4* __restrict__ w2f,
                                               unsigned short* __restrict__ sup2) {
    int t = threadIdx.x;
    int w = t >> 6, lane = t & 63;
    int m0 = (blockIdx.x * 4 + w) * 16;
    int r15 = lane & 15, hi = lane >> 4;

    bf16x8 bfrag[8][3];
#pragma unroll
    for (int ks = 0; ks < 8; ++ks)
#pragma unroll
        for (int n = 0; n < 3; ++n)
            bfrag[ks][n] = __builtin_bit_cast(bf16x8, w2f[(ks * 3 + n) * 64 + lane]);

    f32x4 acc[3];
#pragma unroll
    for (int n = 0; n < 3; ++n) acc[n] = (f32x4){0.f, 0.f, 0.f, 0.f};

    const unsigned short* arow = h1 + (size_t)(m0 + r15) * NHID + hi * 8;
#pragma unroll
    for (int ks = 0; ks < 8; ++ks) {
        bf16x8 a = *(const bf16x8*)(arow + ks * 32);
#pragma unroll
        for (int n = 0; n < 3; ++n)
            acc[n] = __builtin_amdgcn_mfma_f32_16x16x32_bf16(a, bfrag[ks][n], acc[n], 0, 0, 0);
    }
#pragma unroll
    for (int n = 0; n < 3; ++n) {
        int col = n * 16 + r15;
#pragma unroll
        for (int r = 0; r < 4; ++r) {
            int row = m0 + hi * 4 + r;
            sup2[(size_t)row * SUP2_LD + col] = f2bf(acc[n][r]);
        }
    }
}

// ---------------- propagate 2 + b2 + log_softmax: 4 nodes per wave ----------------
// 16-lane group per node; lanes gl<10 hold 4 cols each (8B loads); reductions via
// ds_swizzle xor 8/4/2/1 (stays within each 16-lane group inside a 32-half).
__global__ __launch_bounds__(256) void k_prop2(const unsigned short* __restrict__ sup2,
                                               const int* __restrict__ rowptr,
                                               const uint2* __restrict__ cedge,
                                               const float* __restrict__ b2,
                                               float* __restrict__ out) {
    int gid = blockIdx.x * blockDim.x + threadIdx.x;
    int wv = gid >> 6;
    int lane = gid & 63;
    int grp = lane >> 4;      // 0..3
    int gl = lane & 15;
    int wid = wv * 4 + grp;
    if (wid >= N_NODES) return;
    int beg = rowptr[wid], end = rowptr[wid + 1];
    bool act = gl < 10;
    int c4 = gl * 4;  // cols c4..c4+3
    float acc0 = 0.f, acc1 = 0.f, acc2 = 0.f, acc3 = 0.f;
    int e = beg;
    for (; e + 7 < end; e += 8) {
        uint2 ed[8];
#pragma unroll
        for (int q = 0; q < 8; ++q) ed[q] = cedge[e + q];
        uint2 u[8];
#pragma unroll
        for (int q = 0; q < 8; ++q)
            u[q] = act ? *(const uint2*)(sup2 + (size_t)ed[q].x * SUP2_LD + c4)
                       : make_uint2(0u, 0u);
#pragma unroll
        for (int q = 0; q < 8; ++q) {
            float wq = __builtin_bit_cast(float, ed[q].y);
            float f0, f1, f2, f3;
            bf2x2(u[q].x, f0, f1);
            bf2x2(u[q].y, f2, f3);
            acc0 += wq * f0; acc1 += wq * f1; acc2 += wq * f2; acc3 += wq * f3;
        }
    }
    for (; e < end; ++e) {
        uint2 eq = cedge[e];
        uint2 u = act ? *(const uint2*)(sup2 + (size_t)eq.x * SUP2_LD + c4)
                      : make_uint2(0u, 0u);
        float wq = __builtin_bit_cast(float, eq.y);
        float f0, f1, f2, f3;
        bf2x2(u.x, f0, f1);
        bf2x2(u.y, f2, f3);
        acc0 += wq * f0; acc1 += wq * f1; acc2 += wq * f2; acc3 += wq * f3;
    }
    float v0 = -INFINITY, v1 = -INFINITY, v2 = -INFINITY, v3 = -INFINITY;
    if (act) {
        float4 bb = *(const float4*)(b2 + c4);
        v0 = acc0 + bb.x;
        v1 = acc1 + bb.y;
        v2 = acc2 + bb.z;
        v3 = acc3 + bb.w;
    }
    float m = fmaxf(fmaxf(v0, v1), fmaxf(v2, v3));
    m = fmaxf(m, swzx<0x201F>(m));  // xor 8
    m = fmaxf(m, swzx<0x101F>(m));  // xor 4
    m = fmaxf(m, swzx<0x081F>(m));  // xor 2
    m = fmaxf(m, swzx<0x041F>(m));  // xor 1
    float s = act ? (expf(v0 - m) + expf(v1 - m) + expf(v2 - m) + expf(v3 - m)) : 0.f;
    s += swzx<0x201F>(s);
    s += swzx<0x101F>(s);
    s += swzx<0x081F>(s);
    s += swzx<0x041F>(s);
    if (act) {
        float ls = logf(s);
        float4 o = make_float4(v0 - m - ls, v1 - m - ls, v2 - m - ls, v3 - m - ls);
        *(float4*)(out + (size_t)wid * NCLASS + c4) = o;
    }
}

// ---------------- launch ----------------

extern "C" void kernel_launch(void* const* d_in, const int* in_sizes, int n_in,
                              void* d_out, int out_size, void* d_ws, size_t ws_size,
                              hipStream_t stream) {
    const float* x = (const float*)d_in[0];
    const int* ei = (const int*)d_in[1];
    const float* ew = (const float*)d_in[2];
    const float* W1 = (const float*)d_in[3];
    const float* b1 = (const float*)d_in[4];
    const float* W2 = (const float*)d_in[5];
    const float* b2 = (const float*)d_in[6];
    float* out = (float*)d_out;

    int E = in_sizes[1] / 2;
    const int* src = ei;
    const int* dst = ei + E;

    char* w = (char*)d_ws;
    size_t off = 0;
    auto alloc = [&](size_t bytes) {
        void* p = w + off;
        off += (bytes + 255) & ~(size_t)255;
        return p;
    };
    unsigned short* w1t = (unsigned short*)alloc((size_t)NHID * NFEAT * 2);     // 256 KB
    unsigned short* sup1 = (unsigned short*)alloc((size_t)M_PAD * NHID * 2);    // 51.2 MB
    unsigned short* h1 = (unsigned short*)alloc((size_t)M_PAD * NHID * 2);      // 51.2 MB
    uint2* cedge = (uint2*)alloc((size_t)E * 8);                                // 25.6 MB
    uint2* tmp = (uint2*)alloc((size_t)NBKT * BCAP * 8);                        // 28.7 MB
    unsigned short* sup2 = (unsigned short*)alloc((size_t)M_PAD * SUP2_LD * 2); // 9.6 MB
    int* rowptr = (int*)alloc((size_t)(N_NODES + 1) * 4);
    int* bcur = (int*)alloc((size_t)NBKT * 4);
    uint4* w2f = (uint4*)alloc((size_t)8 * 3 * 64 * 16);  // 24 KB frag-packed W2

    const int BINA_BLOCKS = (E + BINA_CHUNK - 1) / BINA_CHUNK;  // 1042

    k_init<<<1 + CVTW_BLOCKS + 1, 256, 0, stream>>>(bcur, W1, w1t, W2, w2f);
    k_fat<<<GEMM1_BLOCKS + BINA_BLOCKS, 256, 0, stream>>>(x, w1t, sup1,
                                                          src, dst, ew, bcur, tmp, E);
    k_binB<<<NBKT, 256, 0, stream>>>(tmp, bcur, rowptr, cedge);
    k_prop1<<<(N_NODES + 3) / 4, 256, 0, stream>>>(sup1, rowptr, cedge, b1, h1);
    k_gemm2<<<M_PAD / 64, 256, 0, stream>>>(h1, w2f, sup2);
    k_prop2<<<(N_NODES / 4 + 3) / 4, 256, 0, stream>>>(sup2, rowptr, cedge, b2, out);
}

// Round 13
// 478.451 us; speedup vs baseline: 1.1375x; 1.1375x over previous
//
#include <hip/hip_runtime.h>
#include <math.h>

#define N_NODES 100000
#define M_PAD 100096  /* 782*128 */
#define NFEAT 512
#define NHID 256
#define NCLASS 40
#define SUP2_LD 48   /* padded cols for MFMA gemm2 */

#define NBKT 250       /* coarse buckets */
#define NPB 400        /* nodes per bucket: 250*400 = 100000 exactly */
#define BINA_CHUNK 3072 /* 24KB sorted + 3KB bkt8 + 4KB scan = 31.7KB < gemm1's 48KB */
#define BCAP 14336     /* fixed bucket capacity (avg 12800, sigma~113) */

#define GEMM1_BLOCKS (M_PAD / 128) /* 782, one tile each (r11 geometry - r12's 2-tile regressed) */

typedef __attribute__((ext_vector_type(8))) short bf16x8;
typedef __attribute__((ext_vector_type(4))) float f32x4;

__device__ __forceinline__ unsigned short f2bf(float f) {
    unsigned int u = __builtin_bit_cast(unsigned int, f);
    u += 0x7fffu + ((u >> 16) & 1u);  // RNE
    return (unsigned short)(u >> 16);
}
__device__ __forceinline__ void bf2x2(unsigned int u, float& f0, float& f1) {
    f0 = __builtin_bit_cast(float, u << 16);
    f1 = __builtin_bit_cast(float, u & 0xffff0000u);
}
__device__ __forceinline__ void gload16(const void* g, void* l) {
    __builtin_amdgcn_global_load_lds(
        (const __attribute__((address_space(1))) unsigned int*)g,
        (__attribute__((address_space(3))) unsigned int*)l, 16, 0, 0);
}
// conflict-free crossbar xor-swizzle within 32-lane groups (BitMode)
template <int CODE>
__device__ __forceinline__ float swzx(float v) {
    return __builtin_bit_cast(float,
        __builtin_amdgcn_ds_swizzle(__builtin_bit_cast(int, v), CODE));
}

// ---------------- init: bcur bases + w1t transpose + w2 frag-pack ----------------
#define CVTW_BLOCKS 512   /* 256*512/256 */

__global__ __launch_bounds__(256) void k_init(int* __restrict__ bcur,
                                              const float* __restrict__ W1,
                                              unsigned short* __restrict__ w1t,
                                              const float* __restrict__ W2,
                                              uint4* __restrict__ w2f) {
    int b = blockIdx.x;
    int t = threadIdx.x;
    if (b == 0) {
        if (t < NBKT) bcur[t] = t * BCAP;
    } else if (b <= CVTW_BLOCKS) {
        // W1 [512][256] -> w1t [256][512] transposed bf16
        int idx = (b - 1) * 256 + t;
        int n = idx >> 9, k = idx & 511;
        w1t[idx] = f2bf(W1[(size_t)k * NHID + n]);
    } else {
        // W2 [256][40] f32 -> frag-packed bf16 w2f[ks][n][lane] (8*3*64 frags of 16B)
        for (int idx = t; idx < 8 * 3 * 64; idx += 256) {
            int ks = idx / 192;
            int rem = idx - ks * 192;
            int n = rem >> 6;
            int l = rem & 63;
            int col = n * 16 + (l & 15);
            int kbase = ks * 32 + (l >> 4) * 8;
            unsigned short o[8];
#pragma unroll
            for (int j = 0; j < 8; ++j)
                o[j] = (col < NCLASS) ? f2bf(W2[(size_t)(kbase + j) * NCLASS + col]) : 0;
            w2f[idx] = *(const uint4*)o;
        }
    }
}

// ---------------- binA body: LDS counting-sort chunk into 250 buckets ----------------
__device__ __forceinline__ void binA_body(char* smbase, int t, int cblk,
                                          const int* __restrict__ src,
                                          const int* __restrict__ dst,
                                          const float* __restrict__ ew,
                                          int* __restrict__ bcur,
                                          uint2* __restrict__ tmp, int E) {
    uint2* sorted = (uint2*)smbase;                          // 24576 B
    unsigned char* bkt8 = (unsigned char*)(smbase + 24576);  // 3072 B
    int* cnt = (int*)(smbase + 27648);
    int* startv = cnt + 256;
    int* offv = startv + 256;
    int* gb = offv + 256;
    int c0 = cblk * BINA_CHUNK;
    int n = min(BINA_CHUNK, E - c0);
    cnt[t] = 0;
    __syncthreads();
    // pass 1: per-bucket count
    for (int j = t; j < n; j += 256) {
        atomicAdd(&cnt[(unsigned)dst[c0 + j] / NPB], 1);
    }
    __syncthreads();
    int v = cnt[t];
    startv[t] = v;
    __syncthreads();
    for (int o = 1; o < 256; o <<= 1) {
        int a = (t >= o) ? startv[t - o] : 0;
        __syncthreads();
        startv[t] += a;
        __syncthreads();
    }
    int ex = startv[t] - v;  // exclusive start
    __syncthreads();
    startv[t] = ex;
    offv[t] = ex;
    if (t < NBKT) gb[t] = (v > 0) ? atomicAdd(&bcur[t], v) : 0;
    __syncthreads();
    // pass 2: rank + place into LDS (sorted by bucket)
    for (int j = t; j < n; j += 256) {
        int d = dst[c0 + j];
        int b = (unsigned)d / NPB;
        int dl = d - b * NPB;  // < 400, 9 bits
        int r = atomicAdd(&offv[b], 1);
        sorted[r] = make_uint2((unsigned)src[c0 + j] | ((unsigned)dl << 17),
                               __builtin_bit_cast(unsigned, ew[c0 + j]));
        bkt8[r] = (unsigned char)b;
    }
    __syncthreads();
    // drain: linear over sorted -> coalesced bursts per bucket region
    for (int j = t; j < n; j += 256) {
        int b = bkt8[j];
        tmp[gb[b] + (j - startv[b])] = sorted[j];
    }
}

// ---------------- gemm1 body: one 128-row tile, A pipeline split (issue-early/convert-late) ----------------
__device__ __forceinline__ void gemm1_body(char* smem, int t, int mb,
                                           const float* __restrict__ x,
                                           const unsigned short* __restrict__ w1t,
                                           unsigned short* __restrict__ sup1) {
    const int w = t >> 6, lane = t & 63;
    const int m0 = mb * 128;
    const int wm = w >> 1, wn = w & 1;
    const int r15 = lane & 15, hi = lane >> 4;

    f32x4 acc[4][8];
#pragma unroll
    for (int i = 0; i < 4; ++i)
#pragma unroll
        for (int j = 0; j < 8; ++j) acc[i][j] = (f32x4){0.f, 0.f, 0.f, 0.f};

    const char* wsrc = (const char*)w1t;

    float4 pa0, pa1, pa2, pa3;  // A prefetch regs (2 sub-rows x 32B)

#define A_LOAD(kt)                                                                     \
    {                                                                                  \
        int u0 = t, row0 = u0 >> 2, part0 = u0 & 3;                                    \
        int u1 = 256 + t, row1 = u1 >> 2, part1 = u1 & 3;                              \
        int gr0 = m0 + row0, gr1 = m0 + row1;                                          \
        if (gr0 < N_NODES) {                                                           \
            const float* sp = x + (size_t)gr0 * NFEAT + (kt) * 32 + part0 * 8;         \
            pa0 = *(const float4*)sp;                                                  \
            pa1 = *(const float4*)(sp + 4);                                            \
        } else {                                                                       \
            pa0 = pa1 = make_float4(0.f, 0.f, 0.f, 0.f);                               \
        }                                                                              \
        if (gr1 < N_NODES) {                                                           \
            const float* sp = x + (size_t)gr1 * NFEAT + (kt) * 32 + part1 * 8;         \
            pa2 = *(const float4*)sp;                                                  \
            pa3 = *(const float4*)(sp + 4);                                            \
        } else {                                                                       \
            pa2 = pa3 = make_float4(0.f, 0.f, 0.f, 0.f);                               \
        }                                                                              \
    }

#define A_STORE(b)                                                                     \
    {                                                                                  \
        char* Ab = smem + (b) * 8192;                                                  \
        int u0 = t, row0 = u0 >> 2, part0 = u0 & 3;                                    \
        int u1 = 256 + t, row1 = u1 >> 2, part1 = u1 & 3;                              \
        unsigned short ob[8];                                                          \
        ob[0] = f2bf(pa0.x); ob[1] = f2bf(pa0.y); ob[2] = f2bf(pa0.z);                 \
        ob[3] = f2bf(pa0.w); ob[4] = f2bf(pa1.x); ob[5] = f2bf(pa1.y);                 \
        ob[6] = f2bf(pa1.z); ob[7] = f2bf(pa1.w);                                      \
        *(uint4*)(Ab + row0 * 64 + ((part0 ^ ((row0 >> 1) & 3)) << 4)) =               \
            *(const uint4*)ob;                                                         \
        ob[0] = f2bf(pa2.x); ob[1] = f2bf(pa2.y); ob[2] = f2bf(pa2.z);                 \
        ob[3] = f2bf(pa2.w); ob[4] = f2bf(pa3.x); ob[5] = f2bf(pa3.y);                 \
        ob[6] = f2bf(pa3.z); ob[7] = f2bf(pa3.w);                                      \
        *(uint4*)(Ab + row1 * 64 + ((part1 ^ ((row1 >> 1) & 3)) << 4)) =               \
            *(const uint4*)ob;                                                         \
    }

#define B_STAGE(kt, b)                                                                 \
    {                                                                                  \
        char* Bb = smem + 16384 + (b) * 16384;                                         \
        _Pragma("unroll") for (int i = 0; i < 4; ++i) {                                \
            int u = i * 256 + t;                                                       \
            int nrow = u >> 2, part = u & 3;                                           \
            int q = part ^ ((nrow >> 1) & 3);                                          \
            gload16(wsrc + (size_t)nrow * 1024 + (kt) * 64 + q * 16, Bb + u * 16);     \
        }                                                                              \
    }

    A_LOAD(0);
    A_STORE(0);
    B_STAGE(0, 0);
    for (int kt = 0; kt < 16; ++kt) {
        __syncthreads();  // buf (kt&1) ready: B gloads landed, A ds_writes visible
        if (kt < 15) {
            A_LOAD(kt + 1);              // issue x-loads to regs (land during compute)
            B_STAGE(kt + 1, (kt + 1) & 1);  // issue B gloads (land during compute)
        }
        const char* Ab = smem + (kt & 1) * 8192;
        const char* Bb = smem + 16384 + (kt & 1) * 16384;
        bf16x8 a[4], bb[8];
#pragma unroll
        for (int i = 0; i < 4; ++i) {
            int r = wm * 64 + i * 16 + r15;
            a[i] = *(const bf16x8*)(Ab + r * 64 + ((hi ^ ((r >> 1) & 3)) << 4));
        }
#pragma unroll
        for (int j = 0; j < 8; ++j) {
            int n = wn * 128 + j * 16 + r15;
            bb[j] = *(const bf16x8*)(Bb + n * 64 + ((hi ^ ((n >> 1) & 3)) << 4));
        }
#pragma unroll
        for (int i = 0; i < 4; ++i)
#pragma unroll
            for (int j = 0; j < 8; ++j)
                acc[i][j] = __builtin_amdgcn_mfma_f32_16x16x32_bf16(a[i], bb[j], acc[i][j], 0, 0, 0);
        if (kt < 15) A_STORE((kt + 1) & 1);  // convert AFTER compute: loads have landed
    }
#undef A_LOAD
#undef A_STORE
#undef B_STAGE

#pragma unroll
    for (int i = 0; i < 4; ++i) {
        int rowb = m0 + wm * 64 + i * 16 + hi * 4;
#pragma unroll
        for (int j = 0; j < 8; ++j) {
            int col = wn * 128 + j * 16 + r15;
#pragma unroll
            for (int r = 0; r < 4; ++r)
                sup1[(size_t)(rowb + r) * NHID + col] = f2bf(acc[i][j][r]);
        }
    }
}

// ---------------- fat: gemm1 (782 blocks, 1 tile each) first, binA backfills ----------------
__global__ __launch_bounds__(256) void k_fat(const float* __restrict__ x,
                                             const unsigned short* __restrict__ w1t,
                                             unsigned short* __restrict__ sup1,
                                             const int* __restrict__ src,
                                             const int* __restrict__ dst,
                                             const float* __restrict__ ew,
                                             int* __restrict__ bcur,
                                             uint2* __restrict__ tmp, int E) {
    __shared__ __align__(16) char smem[49152];
    int b = blockIdx.x;
    int t = threadIdx.x;
    if (b < GEMM1_BLOCKS) {
        gemm1_body(smem, t, b, x, w1t, sup1);
    } else {
        binA_body(smem, t, b - GEMM1_BLOCKS, src, dst, ew, bcur, tmp, E);
    }
}

// ---------------- binB: bucket-local hist + scan + rowptr write + scatter ----------------
__global__ __launch_bounds__(256) void k_binB(const uint2* __restrict__ tmp,
                                              const int* __restrict__ bcur,
                                              int* __restrict__ rowptr,
                                              uint2* __restrict__ cedge) {
    __shared__ int sc[256];   // scan scratch
    __shared__ int nc[NPB];   // per-node hist
    __shared__ int st[NPB];   // starts -> global cursors
    int b = blockIdx.x, t = threadIdx.x;
    // 1) scan the 250 bucket counts -> my base and count
    int c = (t < NBKT) ? (bcur[t] - t * BCAP) : 0;
    sc[t] = c;
    __syncthreads();
    for (int o = 1; o < 256; o <<= 1) {
        int a = (t >= o) ? sc[t - o] : 0;
        __syncthreads();
        sc[t] += a;
        __syncthreads();
    }
    int base = (b == 0) ? 0 : sc[b - 1];
    int mycnt = sc[b] - base;
    int total = sc[NBKT - 1];
    __syncthreads();
    // 2) LDS histogram of node-local ids
    for (int i = t; i < NPB; i += 256) nc[i] = 0;
    __syncthreads();
    const uint2* srcp = tmp + (size_t)b * BCAP;
    for (int j = t; j < mycnt; j += 256) atomicAdd(&nc[srcp[j].x >> 17], 1);
    __syncthreads();
    // 3) exclusive scan of nc[400] (two 256-chunks)
    int v0 = nc[t];
    sc[t] = v0;
    __syncthreads();
    for (int o = 1; o < 256; o <<= 1) {
        int a = (t >= o) ? sc[t - o] : 0;
        __syncthreads();
        sc[t] += a;
        __syncthreads();
    }
    int tot0 = sc[255];
    st[t] = sc[t] - v0;
    __syncthreads();
    int v1 = (t < NPB - 256) ? nc[256 + t] : 0;
    sc[t] = v1;
    __syncthreads();
    for (int o = 1; o < 256; o <<= 1) {
        int a = (t >= o) ? sc[t - o] : 0;
        __syncthreads();
        sc[t] += a;
        __syncthreads();
    }
    if (t < NPB - 256) st[256 + t] = tot0 + sc[t] - v1;
    __syncthreads();
    // 4) write rowptr slice coalesced; convert st to global cursors
    int n0 = b * NPB;
    for (int i = t; i < NPB; i += 256) {
        int s = base + st[i];
        rowptr[n0 + i] = s;
        st[i] = s;
    }
    if (b == NBKT - 1 && t == 0) rowptr[N_NODES] = total;
    __syncthreads();
    // 5) scatter within block-private window
    for (int j = t; j < mycnt; j += 256) {
        uint2 e = srcp[j];
        int dl = e.x >> 17;
        int addr = atomicAdd(&st[dl], 1);
        cedge[addr] = make_uint2(e.x & 0x1FFFFu, e.y);
    }
}

// ---------------- propagate 1 (bf16 rows, packed edges, 8-unroll) + bias + relu ----------------
__global__ __launch_bounds__(256) void k_prop1(const unsigned short* __restrict__ sup1,
                                               const int* __restrict__ rowptr,
                                               const uint2* __restrict__ cedge,
                                               const float* __restrict__ b1,
                                               unsigned short* __restrict__ h1) {
    int gid = blockIdx.x * blockDim.x + threadIdx.x;
    int wid = gid >> 6;
    int lane = gid & 63;
    if (wid >= N_NODES) return;
    int beg = rowptr[wid], end = rowptr[wid + 1];
    float a0 = 0.f, a1 = 0.f, a2 = 0.f, a3 = 0.f;
    int e = beg;
    for (; e + 7 < end; e += 8) {
        uint2 ed[8];
#pragma unroll
        for (int q = 0; q < 8; ++q) ed[q] = cedge[e + q];
        uint2 r[8];
#pragma unroll
        for (int q = 0; q < 8; ++q)
            r[q] = *(const uint2*)(sup1 + (size_t)ed[q].x * NHID + lane * 4);
#pragma unroll
        for (int q = 0; q < 8; ++q) {
            float wq = __builtin_bit_cast(float, ed[q].y);
            float f0, f1, f2, f3;
            bf2x2(r[q].x, f0, f1);
            bf2x2(r[q].y, f2, f3);
            a0 += wq * f0; a1 += wq * f1; a2 += wq * f2; a3 += wq * f3;
        }
    }
    for (; e < end; ++e) {
        uint2 ed = cedge[e];
        float wq = __builtin_bit_cast(float, ed.y);
        uint2 rv = *(const uint2*)(sup1 + (size_t)ed.x * NHID + lane * 4);
        float f0, f1, f2, f3;
        bf2x2(rv.x, f0, f1);
        bf2x2(rv.y, f2, f3);
        a0 += wq * f0; a1 += wq * f1; a2 += wq * f2; a3 += wq * f3;
    }
    float4 bv = *(const float4*)(b1 + lane * 4);
    a0 = fmaxf(a0 + bv.x, 0.f);
    a1 = fmaxf(a1 + bv.y, 0.f);
    a2 = fmaxf(a2 + bv.z, 0.f);
    a3 = fmaxf(a3 + bv.w, 0.f);
    unsigned short o[4] = {f2bf(a0), f2bf(a1), f2bf(a2), f2bf(a3)};
    *(uint2*)(h1 + (size_t)wid * NHID + lane * 4) = *(const uint2*)o;
}

// ---------------- GEMM2 (MFMA): sup2[M_PAD][48] = h1 @ W2  (W2 frag-packed) ----------------
__global__ __launch_bounds__(256) void k_gemm2(const unsigned short* __restrict__ h1,
                                               const uint4* __restrict__ w2f,
                                               unsigned short* __restrict__ sup2) {
    int t = threadIdx.x;
    int w = t >> 6, lane = t & 63;
    int m0 = (blockIdx.x * 4 + w) * 16;
    int r15 = lane & 15, hi = lane >> 4;

    bf16x8 bfrag[8][3];
#pragma unroll
    for (int ks = 0; ks < 8; ++ks)
#pragma unroll
        for (int n = 0; n < 3; ++n)
            bfrag[ks][n] = __builtin_bit_cast(bf16x8, w2f[(ks * 3 + n) * 64 + lane]);

    f32x4 acc[3];
#pragma unroll
    for (int n = 0; n < 3; ++n) acc[n] = (f32x4){0.f, 0.f, 0.f, 0.f};

    const unsigned short* arow = h1 + (size_t)(m0 + r15) * NHID + hi * 8;
#pragma unroll
    for (int ks = 0; ks < 8; ++ks) {
        bf16x8 a = *(const bf16x8*)(arow + ks * 32);
#pragma unroll
        for (int n = 0; n < 3; ++n)
            acc[n] = __builtin_amdgcn_mfma_f32_16x16x32_bf16(a, bfrag[ks][n], acc[n], 0, 0, 0);
    }
#pragma unroll
    for (int n = 0; n < 3; ++n) {
        int col = n * 16 + r15;
#pragma unroll
        for (int r = 0; r < 4; ++r) {
            int row = m0 + hi * 4 + r;
            sup2[(size_t)row * SUP2_LD + col] = f2bf(acc[n][r]);
        }
    }
}

// ---------------- propagate 2 + b2 + log_softmax: 4 nodes per wave ----------------
__global__ __launch_bounds__(256) void k_prop2(const unsigned short* __restrict__ sup2,
                                               const int* __restrict__ rowptr,
                                               const uint2* __restrict__ cedge,
                                               const float* __restrict__ b2,
                                               float* __restrict__ out) {
    int gid = blockIdx.x * blockDim.x + threadIdx.x;
    int wv = gid >> 6;
    int lane = gid & 63;
    int grp = lane >> 4;      // 0..3
    int gl = lane & 15;
    int wid = wv * 4 + grp;
    if (wid >= N_NODES) return;
    int beg = rowptr[wid], end = rowptr[wid + 1];
    bool act = gl < 10;
    int c4 = gl * 4;  // cols c4..c4+3
    float acc0 = 0.f, acc1 = 0.f, acc2 = 0.f, acc3 = 0.f;
    int e = beg;
    for (; e + 7 < end; e += 8) {
        uint2 ed[8];
#pragma unroll
        for (int q = 0; q < 8; ++q) ed[q] = cedge[e + q];
        uint2 u[8];
#pragma unroll
        for (int q = 0; q < 8; ++q)
            u[q] = act ? *(const uint2*)(sup2 + (size_t)ed[q].x * SUP2_LD + c4)
                       : make_uint2(0u, 0u);
#pragma unroll
        for (int q = 0; q < 8; ++q) {
            float wq = __builtin_bit_cast(float, ed[q].y);
            float f0, f1, f2, f3;
            bf2x2(u[q].x, f0, f1);
            bf2x2(u[q].y, f2, f3);
            acc0 += wq * f0; acc1 += wq * f1; acc2 += wq * f2; acc3 += wq * f3;
        }
    }
    for (; e < end; ++e) {
        uint2 eq = cedge[e];
        uint2 u = act ? *(const uint2*)(sup2 + (size_t)eq.x * SUP2_LD + c4)
                      : make_uint2(0u, 0u);
        float wq = __builtin_bit_cast(float, eq.y);
        float f0, f1, f2, f3;
        bf2x2(u.x, f0, f1);
        bf2x2(u.y, f2, f3);
        acc0 += wq * f0; acc1 += wq * f1; acc2 += wq * f2; acc3 += wq * f3;
    }
    float v0 = -INFINITY, v1 = -INFINITY, v2 = -INFINITY, v3 = -INFINITY;
    if (act) {
        float4 bb = *(const float4*)(b2 + c4);
        v0 = acc0 + bb.x;
        v1 = acc1 + bb.y;
        v2 = acc2 + bb.z;
        v3 = acc3 + bb.w;
    }
    float m = fmaxf(fmaxf(v0, v1), fmaxf(v2, v3));
    m = fmaxf(m, swzx<0x201F>(m));  // xor 8
    m = fmaxf(m, swzx<0x101F>(m));  // xor 4
    m = fmaxf(m, swzx<0x081F>(m));  // xor 2
    m = fmaxf(m, swzx<0x041F>(m));  // xor 1
    float s = act ? (expf(v0 - m) + expf(v1 - m) + expf(v2 - m) + expf(v3 - m)) : 0.f;
    s += swzx<0x201F>(s);
    s += swzx<0x101F>(s);
    s += swzx<0x081F>(s);
    s += swzx<0x041F>(s);
    if (act) {
        float ls = logf(s);
        float4 o = make_float4(v0 - m - ls, v1 - m - ls, v2 - m - ls, v3 - m - ls);
        *(float4*)(out + (size_t)wid * NCLASS + c4) = o;
    }
}

// ---------------- launch ----------------

extern "C" void kernel_launch(void* const* d_in, const int* in_sizes, int n_in,
                              void* d_out, int out_size, void* d_ws, size_t ws_size,
                              hipStream_t stream) {
    const float* x = (const float*)d_in[0];
    const int* ei = (const int*)d_in[1];
    const float* ew = (const float*)d_in[2];
    const float* W1 = (const float*)d_in[3];
    const float* b1 = (const float*)d_in[4];
    const float* W2 = (const float*)d_in[5];
    const float* b2 = (const float*)d_in[6];
    float* out = (float*)d_out;

    int E = in_sizes[1] / 2;
    const int* src = ei;
    const int* dst = ei + E;

    char* w = (char*)d_ws;
    size_t off = 0;
    auto alloc = [&](size_t bytes) {
        void* p = w + off;
        off += (bytes + 255) & ~(size_t)255;
        return p;
    };
    unsigned short* w1t = (unsigned short*)alloc((size_t)NHID * NFEAT * 2);     // 256 KB
    unsigned short* sup1 = (unsigned short*)alloc((size_t)M_PAD * NHID * 2);    // 51.2 MB
    unsigned short* h1 = (unsigned short*)alloc((size_t)M_PAD * NHID * 2);      // 51.2 MB
    uint2* cedge = (uint2*)alloc((size_t)E * 8);                                // 25.6 MB
    uint2* tmp = (uint2*)alloc((size_t)NBKT * BCAP * 8);                        // 28.7 MB
    unsigned short* sup2 = (unsigned short*)alloc((size_t)M_PAD * SUP2_LD * 2); // 9.6 MB
    int* rowptr = (int*)alloc((size_t)(N_NODES + 1) * 4);
    int* bcur = (int*)alloc((size_t)NBKT * 4);
    uint4* w2f = (uint4*)alloc((size_t)8 * 3 * 64 * 16);  // 24 KB frag-packed W2

    const int BINA_BLOCKS = (E + BINA_CHUNK - 1) / BINA_CHUNK;  // 1042

    k_init<<<1 + CVTW_BLOCKS + 1, 256, 0, stream>>>(bcur, W1, w1t, W2, w2f);
    k_fat<<<GEMM1_BLOCKS + BINA_BLOCKS, 256, 0, stream>>>(x, w1t, sup1,
                                                          src, dst, ew, bcur, tmp, E);
    k_binB<<<NBKT, 256, 0, stream>>>(tmp, bcur, rowptr, cedge);
    k_prop1<<<(N_NODES + 3) / 4, 256, 0, stream>>>(sup1, rowptr, cedge, b1, h1);
    k_gemm2<<<M_PAD / 64, 256, 0, stream>>>(h1, w2f, sup2);
    k_prop2<<<(N_NODES / 4 + 3) / 4, 256, 0, stream>>>(sup2, rowptr, cedge, b2, out);
}

// Round 14
// 464.036 us; speedup vs baseline: 1.1728x; 1.0311x over previous
//
#include <hip/hip_runtime.h>
#include <math.h>

#define N_NODES 100000
#define M_PAD 100096  /* 782*128 */
#define NFEAT 512
#define NHID 256
#define NCLASS 40
#define SUP2_LD 48   /* padded cols for MFMA gemm2 */

#define NBKT 200       /* coarse buckets */
#define NPB 500        /* nodes per bucket: 200*500 = 100000 exactly */
#define BINA_CHUNK 3072 /* 24KB sorted + 3KB bkt8 + 4KB scan = 31.7KB */
#define BCAP 17920     /* fixed bucket capacity (avg 16000, sigma~126, +15 sigma) */

#define GEMM1_BLOCKS (M_PAD / 128) /* 782 */

typedef __attribute__((ext_vector_type(8))) short bf16x8;
typedef __attribute__((ext_vector_type(4))) float f32x4;

__device__ __forceinline__ unsigned short f2bf(float f) {
    unsigned int u = __builtin_bit_cast(unsigned int, f);
    u += 0x7fffu + ((u >> 16) & 1u);  // RNE
    return (unsigned short)(u >> 16);
}
__device__ __forceinline__ void bf2x2(unsigned int u, float& f0, float& f1) {
    f0 = __builtin_bit_cast(float, u << 16);
    f1 = __builtin_bit_cast(float, u & 0xffff0000u);
}
__device__ __forceinline__ void gload16(const void* g, void* l) {
    __builtin_amdgcn_global_load_lds(
        (const __attribute__((address_space(1))) unsigned int*)g,
        (__attribute__((address_space(3))) unsigned int*)l, 16, 0, 0);
}
// conflict-free crossbar xor-swizzle within 32-lane groups (BitMode)
template <int CODE>
__device__ __forceinline__ float swzx(float v) {
    return __builtin_bit_cast(float,
        __builtin_amdgcn_ds_swizzle(__builtin_bit_cast(int, v), CODE));
}

// ---------------- binA body: LDS counting-sort chunk into 200 buckets ----------------
// bcur is ZERO-BASED (pure counts); tmp slot = bucket*BCAP + running offset.
__device__ __forceinline__ void binA_body(char* smbase, int t, int cblk,
                                          const int* __restrict__ src,
                                          const int* __restrict__ dst,
                                          const float* __restrict__ ew,
                                          int* __restrict__ bcur,
                                          uint2* __restrict__ tmp, int E) {
    uint2* sorted = (uint2*)smbase;                          // 24576 B
    unsigned char* bkt8 = (unsigned char*)(smbase + 24576);  // 3072 B
    int* cnt = (int*)(smbase + 27648);
    int* startv = cnt + 256;
    int* offv = startv + 256;
    int* gb = offv + 256;
    int c0 = cblk * BINA_CHUNK;
    int n = min(BINA_CHUNK, E - c0);
    cnt[t] = 0;
    __syncthreads();
    // pass 1: per-bucket count
    for (int j = t; j < n; j += 256) {
        atomicAdd(&cnt[(unsigned)dst[c0 + j] / NPB], 1);
    }
    __syncthreads();
    int v = cnt[t];
    startv[t] = v;
    __syncthreads();
    for (int o = 1; o < 256; o <<= 1) {
        int a = (t >= o) ? startv[t - o] : 0;
        __syncthreads();
        startv[t] += a;
        __syncthreads();
    }
    int ex = startv[t] - v;  // exclusive start
    __syncthreads();
    startv[t] = ex;
    offv[t] = ex;
    if (t < NBKT) gb[t] = (v > 0) ? atomicAdd(&bcur[t], v) : 0;
    __syncthreads();
    // pass 2: rank + place into LDS (sorted by bucket)
    for (int j = t; j < n; j += 256) {
        int d = dst[c0 + j];
        int b = (unsigned)d / NPB;
        int dl = d - b * NPB;  // < 500, 9 bits
        int r = atomicAdd(&offv[b], 1);
        sorted[r] = make_uint2((unsigned)src[c0 + j] | ((unsigned)dl << 17),
                               __builtin_bit_cast(unsigned, ew[c0 + j]));
        bkt8[r] = (unsigned char)b;
    }
    __syncthreads();
    // drain: linear over sorted -> coalesced bursts per bucket region
    for (int j = t; j < n; j += 256) {
        int b = bkt8[j];
        tmp[(size_t)b * BCAP + gb[b] + (j - startv[b])] = sorted[j];
    }
}

// ---------------- k_pre: binA (blocks 0..1041) + w1t transpose + w2 frag-pack ----------------
#define CVTW_BLOCKS 512   /* 256*512/256 */

__global__ __launch_bounds__(256) void k_pre(const int* __restrict__ src,
                                             const int* __restrict__ dst,
                                             const float* __restrict__ ew,
                                             int* __restrict__ bcur,
                                             uint2* __restrict__ tmp, int E, int binaBlocks,
                                             const float* __restrict__ W1,
                                             unsigned short* __restrict__ w1t,
                                             const float* __restrict__ W2,
                                             uint4* __restrict__ w2f) {
    __shared__ __align__(16) char smem[31744];
    int b = blockIdx.x;
    int t = threadIdx.x;
    if (b < binaBlocks) {
        binA_body(smem, t, b, src, dst, ew, bcur, tmp, E);
    } else if (b < binaBlocks + CVTW_BLOCKS) {
        // W1 [512][256] -> w1t [256][512] transposed bf16
        int idx = (b - binaBlocks) * 256 + t;
        int n = idx >> 9, k = idx & 511;
        w1t[idx] = f2bf(W1[(size_t)k * NHID + n]);
    } else {
        // W2 [256][40] f32 -> frag-packed bf16 w2f[ks][n][lane] (8*3*64 frags of 16B)
        for (int idx = t; idx < 8 * 3 * 64; idx += 256) {
            int ks = idx / 192;
            int rem = idx - ks * 192;
            int n = rem >> 6;
            int l = rem & 63;
            int col = n * 16 + (l & 15);
            int kbase = ks * 32 + (l >> 4) * 8;
            unsigned short o[8];
#pragma unroll
            for (int j = 0; j < 8; ++j)
                o[j] = (col < NCLASS) ? f2bf(W2[(size_t)(kbase + j) * NCLASS + col]) : 0;
            w2f[idx] = *(const uint4*)o;
        }
    }
}

// ---------------- binB body: bucket-local hist + scan + rowptr write + scatter ----------------
__device__ __forceinline__ void binB_body(char* smbase, int b, int t,
                                          const uint2* __restrict__ tmp,
                                          const int* __restrict__ bcur,
                                          int* __restrict__ rowptr,
                                          uint2* __restrict__ cedge) {
    int* sc = (int*)smbase;          // 256 ints
    int* nc = sc + 256;              // NPB=500 ints
    int* st = nc + NPB;              // NPB=500 ints
    // 1) scan the 200 bucket counts -> my base and count
    int c = (t < NBKT) ? bcur[t] : 0;
    sc[t] = c;
    __syncthreads();
    for (int o = 1; o < 256; o <<= 1) {
        int a = (t >= o) ? sc[t - o] : 0;
        __syncthreads();
        sc[t] += a;
        __syncthreads();
    }
    int base = (b == 0) ? 0 : sc[b - 1];
    int mycnt = sc[b] - base;
    int total = sc[NBKT - 1];
    __syncthreads();
    // 2) LDS histogram of node-local ids
    for (int i = t; i < NPB; i += 256) nc[i] = 0;
    __syncthreads();
    const uint2* srcp = tmp + (size_t)b * BCAP;
    for (int j = t; j < mycnt; j += 256) atomicAdd(&nc[srcp[j].x >> 17], 1);
    __syncthreads();
    // 3) exclusive scan of nc[500] (chunks 256 + 244)
    int v0 = nc[t];
    sc[t] = v0;
    __syncthreads();
    for (int o = 1; o < 256; o <<= 1) {
        int a = (t >= o) ? sc[t - o] : 0;
        __syncthreads();
        sc[t] += a;
        __syncthreads();
    }
    int tot0 = sc[255];
    st[t] = sc[t] - v0;
    __syncthreads();
    int v1 = (t < NPB - 256) ? nc[256 + t] : 0;
    sc[t] = v1;
    __syncthreads();
    for (int o = 1; o < 256; o <<= 1) {
        int a = (t >= o) ? sc[t - o] : 0;
        __syncthreads();
        sc[t] += a;
        __syncthreads();
    }
    if (t < NPB - 256) st[256 + t] = tot0 + sc[t] - v1;
    __syncthreads();
    // 4) write rowptr slice coalesced; convert st to global cursors
    int n0 = b * NPB;
    for (int i = t; i < NPB; i += 256) {
        int s = base + st[i];
        rowptr[n0 + i] = s;
        st[i] = s;
    }
    if (b == NBKT - 1 && t == 0) rowptr[N_NODES] = total;
    __syncthreads();
    // 5) scatter within block-private window
    for (int j = t; j < mycnt; j += 256) {
        uint2 e = srcp[j];
        int dl = e.x >> 17;
        int addr = atomicAdd(&st[dl], 1);
        cedge[addr] = make_uint2(e.x & 0x1FFFFu, e.y);
    }
}

// ---------------- gemm1 body: one 128-row tile, A pipeline split (issue-early/convert-late) ----------------
__device__ __forceinline__ void gemm1_body(char* smem, int t, int mb,
                                           const float* __restrict__ x,
                                           const unsigned short* __restrict__ w1t,
                                           unsigned short* __restrict__ sup1) {
    const int w = t >> 6, lane = t & 63;
    const int m0 = mb * 128;
    const int wm = w >> 1, wn = w & 1;
    const int r15 = lane & 15, hi = lane >> 4;

    f32x4 acc[4][8];
#pragma unroll
    for (int i = 0; i < 4; ++i)
#pragma unroll
        for (int j = 0; j < 8; ++j) acc[i][j] = (f32x4){0.f, 0.f, 0.f, 0.f};

    const char* wsrc = (const char*)w1t;

    float4 pa0, pa1, pa2, pa3;  // A prefetch regs (2 sub-rows x 32B)

#define A_LOAD(kt)                                                                     \
    {                                                                                  \
        int u0 = t, row0 = u0 >> 2, part0 = u0 & 3;                                    \
        int u1 = 256 + t, row1 = u1 >> 2, part1 = u1 & 3;                              \
        int gr0 = m0 + row0, gr1 = m0 + row1;                                          \
        if (gr0 < N_NODES) {                                                           \
            const float* sp = x + (size_t)gr0 * NFEAT + (kt) * 32 + part0 * 8;         \
            pa0 = *(const float4*)sp;                                                  \
            pa1 = *(const float4*)(sp + 4);                                            \
        } else {                                                                       \
            pa0 = pa1 = make_float4(0.f, 0.f, 0.f, 0.f);                               \
        }                                                                              \
        if (gr1 < N_NODES) {                                                           \
            const float* sp = x + (size_t)gr1 * NFEAT + (kt) * 32 + part1 * 8;         \
            pa2 = *(const float4*)sp;                                                  \
            pa3 = *(const float4*)(sp + 4);                                            \
        } else {                                                                       \
            pa2 = pa3 = make_float4(0.f, 0.f, 0.f, 0.f);                               \
        }                                                                              \
    }

#define A_STORE(b)                                                                     \
    {                                                                                  \
        char* Ab = smem + (b) * 8192;                                                  \
        int u0 = t, row0 = u0 >> 2, part0 = u0 & 3;                                    \
        int u1 = 256 + t, row1 = u1 >> 2, part1 = u1 & 3;                              \
        unsigned short ob[8];                                                          \
        ob[0] = f2bf(pa0.x); ob[1] = f2bf(pa0.y); ob[2] = f2bf(pa0.z);                 \
        ob[3] = f2bf(pa0.w); ob[4] = f2bf(pa1.x); ob[5] = f2bf(pa1.y);                 \
        ob[6] = f2bf(pa1.z); ob[7] = f2bf(pa1.w);                                      \
        *(uint4*)(Ab + row0 * 64 + ((part0 ^ ((row0 >> 1) & 3)) << 4)) =               \
            *(const uint4*)ob;                                                         \
        ob[0] = f2bf(pa2.x); ob[1] = f2bf(pa2.y); ob[2] = f2bf(pa2.z);                 \
        ob[3] = f2bf(pa2.w); ob[4] = f2bf(pa3.x); ob[5] = f2bf(pa3.y);                 \
        ob[6] = f2bf(pa3.z); ob[7] = f2bf(pa3.w);                                      \
        *(uint4*)(Ab + row1 * 64 + ((part1 ^ ((row1 >> 1) & 3)) << 4)) =               \
            *(const uint4*)ob;                                                         \
    }

#define B_STAGE(kt, b)                                                                 \
    {                                                                                  \
        char* Bb = smem + 16384 + (b) * 16384;                                         \
        _Pragma("unroll") for (int i = 0; i < 4; ++i) {                                \
            int u = i * 256 + t;                                                       \
            int nrow = u >> 2, part = u & 3;                                           \
            int q = part ^ ((nrow >> 1) & 3);                                          \
            gload16(wsrc + (size_t)nrow * 1024 + (kt) * 64 + q * 16, Bb + u * 16);     \
        }                                                                              \
    }

    A_LOAD(0);
    A_STORE(0);
    B_STAGE(0, 0);
    for (int kt = 0; kt < 16; ++kt) {
        __syncthreads();  // buf (kt&1) ready: B gloads landed, A ds_writes visible
        if (kt < 15) {
            A_LOAD(kt + 1);                 // issue x-loads to regs (land during compute)
            B_STAGE(kt + 1, (kt + 1) & 1);  // issue B gloads (land during compute)
        }
        const char* Ab = smem + (kt & 1) * 8192;
        const char* Bb = smem + 16384 + (kt & 1) * 16384;
        bf16x8 a[4], bb[8];
#pragma unroll
        for (int i = 0; i < 4; ++i) {
            int r = wm * 64 + i * 16 + r15;
            a[i] = *(const bf16x8*)(Ab + r * 64 + ((hi ^ ((r >> 1) & 3)) << 4));
        }
#pragma unroll
        for (int j = 0; j < 8; ++j) {
            int n = wn * 128 + j * 16 + r15;
            bb[j] = *(const bf16x8*)(Bb + n * 64 + ((hi ^ ((n >> 1) & 3)) << 4));
        }
#pragma unroll
        for (int i = 0; i < 4; ++i)
#pragma unroll
            for (int j = 0; j < 8; ++j)
                acc[i][j] = __builtin_amdgcn_mfma_f32_16x16x32_bf16(a[i], bb[j], acc[i][j], 0, 0, 0);
        if (kt < 15) A_STORE((kt + 1) & 1);  // convert AFTER compute: loads have landed
    }
#undef A_LOAD
#undef A_STORE
#undef B_STAGE

#pragma unroll
    for (int i = 0; i < 4; ++i) {
        int rowb = m0 + wm * 64 + i * 16 + hi * 4;
#pragma unroll
        for (int j = 0; j < 8; ++j) {
            int col = wn * 128 + j * 16 + r15;
#pragma unroll
            for (int r = 0; r < 4; ++r)
                sup1[(size_t)(rowb + r) * NHID + col] = f2bf(acc[i][j][r]);
        }
    }
}

// ---------------- fat: binB (blocks 0..199, long poles start first) + gemm1 ----------------
__global__ __launch_bounds__(256) void k_fat(const uint2* __restrict__ tmp,
                                             const int* __restrict__ bcur,
                                             int* __restrict__ rowptr,
                                             uint2* __restrict__ cedge,
                                             const float* __restrict__ x,
                                             const unsigned short* __restrict__ w1t,
                                             unsigned short* __restrict__ sup1) {
    __shared__ __align__(16) char smem[49152];
    int b = blockIdx.x;
    int t = threadIdx.x;
    if (b < NBKT) {
        binB_body(smem, b, t, tmp, bcur, rowptr, cedge);
    } else {
        gemm1_body(smem, t, b - NBKT, x, w1t, sup1);
    }
}

// ---------------- propagate 1 (bf16 rows, packed edges, 8-unroll) + bias + relu ----------------
__global__ __launch_bounds__(256) void k_prop1(const unsigned short* __restrict__ sup1,
                                               const int* __restrict__ rowptr,
                                               const uint2* __restrict__ cedge,
                                               const float* __restrict__ b1,
                                               unsigned short* __restrict__ h1) {
    int gid = blockIdx.x * blockDim.x + threadIdx.x;
    int wid = gid >> 6;
    int lane = gid & 63;
    if (wid >= N_NODES) return;
    int beg = rowptr[wid], end = rowptr[wid + 1];
    float a0 = 0.f, a1 = 0.f, a2 = 0.f, a3 = 0.f;
    int e = beg;
    for (; e + 7 < end; e += 8) {
        uint2 ed[8];
#pragma unroll
        for (int q = 0; q < 8; ++q) ed[q] = cedge[e + q];
        uint2 r[8];
#pragma unroll
        for (int q = 0; q < 8; ++q)
            r[q] = *(const uint2*)(sup1 + (size_t)ed[q].x * NHID + lane * 4);
#pragma unroll
        for (int q = 0; q < 8; ++q) {
            float wq = __builtin_bit_cast(float, ed[q].y);
            float f0, f1, f2, f3;
            bf2x2(r[q].x, f0, f1);
            bf2x2(r[q].y, f2, f3);
            a0 += wq * f0; a1 += wq * f1; a2 += wq * f2; a3 += wq * f3;
        }
    }
    for (; e < end; ++e) {
        uint2 ed = cedge[e];
        float wq = __builtin_bit_cast(float, ed.y);
        uint2 rv = *(const uint2*)(sup1 + (size_t)ed.x * NHID + lane * 4);
        float f0, f1, f2, f3;
        bf2x2(rv.x, f0, f1);
        bf2x2(rv.y, f2, f3);
        a0 += wq * f0; a1 += wq * f1; a2 += wq * f2; a3 += wq * f3;
    }
    float4 bv = *(const float4*)(b1 + lane * 4);
    a0 = fmaxf(a0 + bv.x, 0.f);
    a1 = fmaxf(a1 + bv.y, 0.f);
    a2 = fmaxf(a2 + bv.z, 0.f);
    a3 = fmaxf(a3 + bv.w, 0.f);
    unsigned short o[4] = {f2bf(a0), f2bf(a1), f2bf(a2), f2bf(a3)};
    *(uint2*)(h1 + (size_t)wid * NHID + lane * 4) = *(const uint2*)o;
}

// ---------------- GEMM2 (MFMA): sup2[M_PAD][48] = h1 @ W2  (W2 frag-packed) ----------------
__global__ __launch_bounds__(256) void k_gemm2(const unsigned short* __restrict__ h1,
                                               const uint4* __restrict__ w2f,
                                               unsigned short* __restrict__ sup2) {
    int t = threadIdx.x;
    int w = t >> 6, lane = t & 63;
    int m0 = (blockIdx.x * 4 + w) * 16;
    int r15 = lane & 15, hi = lane >> 4;

    bf16x8 bfrag[8][3];
#pragma unroll
    for (int ks = 0; ks < 8; ++ks)
#pragma unroll
        for (int n = 0; n < 3; ++n)
            bfrag[ks][n] = __builtin_bit_cast(bf16x8, w2f[(ks * 3 + n) * 64 + lane]);

    f32x4 acc[3];
#pragma unroll
    for (int n = 0; n < 3; ++n) acc[n] = (f32x4){0.f, 0.f, 0.f, 0.f};

    const unsigned short* arow = h1 + (size_t)(m0 + r15) * NHID + hi * 8;
#pragma unroll
    for (int ks = 0; ks < 8; ++ks) {
        bf16x8 a = *(const bf16x8*)(arow + ks * 32);
#pragma unroll
        for (int n = 0; n < 3; ++n)
            acc[n] = __builtin_amdgcn_mfma_f32_16x16x32_bf16(a, bfrag[ks][n], acc[n], 0, 0, 0);
    }
#pragma unroll
    for (int n = 0; n < 3; ++n) {
        int col = n * 16 + r15;
#pragma unroll
        for (int r = 0; r < 4; ++r) {
            int row = m0 + hi * 4 + r;
            sup2[(size_t)row * SUP2_LD + col] = f2bf(acc[n][r]);
        }
    }
}

// ---------------- propagate 2 + b2 + log_softmax: 4 nodes per wave ----------------
__global__ __launch_bounds__(256) void k_prop2(const unsigned short* __restrict__ sup2,
                                               const int* __restrict__ rowptr,
                                               const uint2* __restrict__ cedge,
                                               const float* __restrict__ b2,
                                               float* __restrict__ out) {
    int gid = blockIdx.x * blockDim.x + threadIdx.x;
    int wv = gid >> 6;
    int lane = gid & 63;
    int grp = lane >> 4;      // 0..3
    int gl = lane & 15;
    int wid = wv * 4 + grp;
    if (wid >= N_NODES) return;
    int beg = rowptr[wid], end = rowptr[wid + 1];
    bool act = gl < 10;
    int c4 = gl * 4;  // cols c4..c4+3
    float acc0 = 0.f, acc1 = 0.f, acc2 = 0.f, acc3 = 0.f;
    int e = beg;
    for (; e + 7 < end; e += 8) {
        uint2 ed[8];
#pragma unroll
        for (int q = 0; q < 8; ++q) ed[q] = cedge[e + q];
        uint2 u[8];
#pragma unroll
        for (int q = 0; q < 8; ++q)
            u[q] = act ? *(const uint2*)(sup2 + (size_t)ed[q].x * SUP2_LD + c4)
                       : make_uint2(0u, 0u);
#pragma unroll
        for (int q = 0; q < 8; ++q) {
            float wq = __builtin_bit_cast(float, ed[q].y);
            float f0, f1, f2, f3;
            bf2x2(u[q].x, f0, f1);
            bf2x2(u[q].y, f2, f3);
            acc0 += wq * f0; acc1 += wq * f1; acc2 += wq * f2; acc3 += wq * f3;
        }
    }
    for (; e < end; ++e) {
        uint2 eq = cedge[e];
        uint2 u = act ? *(const uint2*)(sup2 + (size_t)eq.x * SUP2_LD + c4)
                      : make_uint2(0u, 0u);
        float wq = __builtin_bit_cast(float, eq.y);
        float f0, f1, f2, f3;
        bf2x2(u.x, f0, f1);
        bf2x2(u.y, f2, f3);
        acc0 += wq * f0; acc1 += wq * f1; acc2 += wq * f2; acc3 += wq * f3;
    }
    float v0 = -INFINITY, v1 = -INFINITY, v2 = -INFINITY, v3 = -INFINITY;
    if (act) {
        float4 bb = *(const float4*)(b2 + c4);
        v0 = acc0 + bb.x;
        v1 = acc1 + bb.y;
        v2 = acc2 + bb.z;
        v3 = acc3 + bb.w;
    }
    float m = fmaxf(fmaxf(v0, v1), fmaxf(v2, v3));
    m = fmaxf(m, swzx<0x201F>(m));  // xor 8
    m = fmaxf(m, swzx<0x101F>(m));  // xor 4
    m = fmaxf(m, swzx<0x081F>(m));  // xor 2
    m = fmaxf(m, swzx<0x041F>(m));  // xor 1
    float s = act ? (expf(v0 - m) + expf(v1 - m) + expf(v2 - m) + expf(v3 - m)) : 0.f;
    s += swzx<0x201F>(s);
    s += swzx<0x101F>(s);
    s += swzx<0x081F>(s);
    s += swzx<0x041F>(s);
    if (act) {
        float ls = logf(s);
        float4 o = make_float4(v0 - m - ls, v1 - m - ls, v2 - m - ls, v3 - m - ls);
        *(float4*)(out + (size_t)wid * NCLASS + c4) = o;
    }
}

// ---------------- launch ----------------

extern "C" void kernel_launch(void* const* d_in, const int* in_sizes, int n_in,
                              void* d_out, int out_size, void* d_ws, size_t ws_size,
                              hipStream_t stream) {
    const float* x = (const float*)d_in[0];
    const int* ei = (const int*)d_in[1];
    const float* ew = (const float*)d_in[2];
    const float* W1 = (const float*)d_in[3];
    const float* b1 = (const float*)d_in[4];
    const float* W2 = (const float*)d_in[5];
    const float* b2 = (const float*)d_in[6];
    float* out = (float*)d_out;

    int E = in_sizes[1] / 2;
    const int* src = ei;
    const int* dst = ei + E;

    char* w = (char*)d_ws;
    size_t off = 0;
    auto alloc = [&](size_t bytes) {
        void* p = w + off;
        off += (bytes + 255) & ~(size_t)255;
        return p;
    };
    unsigned short* w1t = (unsigned short*)alloc((size_t)NHID * NFEAT * 2);     // 256 KB
    unsigned short* sup1 = (unsigned short*)alloc((size_t)M_PAD * NHID * 2);    // 51.2 MB
    unsigned short* h1 = (unsigned short*)alloc((size_t)M_PAD * NHID * 2);      // 51.2 MB
    uint2* cedge = (uint2*)alloc((size_t)E * 8);                                // 25.6 MB
    uint2* tmp = (uint2*)alloc((size_t)NBKT * BCAP * 8);                        // 28.7 MB
    unsigned short* sup2 = (unsigned short*)alloc((size_t)M_PAD * SUP2_LD * 2); // 9.6 MB
    int* rowptr = (int*)alloc((size_t)(N_NODES + 1) * 4);
    int* bcur = (int*)alloc((size_t)NBKT * 4);
    uint4* w2f = (uint4*)alloc((size_t)8 * 3 * 64 * 16);  // 24 KB frag-packed W2

    const int BINA_BLOCKS = (E + BINA_CHUNK - 1) / BINA_CHUNK;  // 1042

    hipMemsetAsync(bcur, 0, (size_t)NBKT * 4, stream);
    k_pre<<<BINA_BLOCKS + CVTW_BLOCKS + 1, 256, 0, stream>>>(src, dst, ew, bcur, tmp, E,
                                                             BINA_BLOCKS, W1, w1t, W2, w2f);
    k_fat<<<NBKT + GEMM1_BLOCKS, 256, 0, stream>>>(tmp, bcur, rowptr, cedge, x, w1t, sup1);
    k_prop1<<<(N_NODES + 3) / 4, 256, 0, stream>>>(sup1, rowptr, cedge, b1, h1);
    k_gemm2<<<M_PAD / 64, 256, 0, stream>>>(h1, w2f, sup2);
    k_prop2<<<(N_NODES / 4 + 3) / 4, 256, 0, stream>>>(sup2, rowptr, cedge, b2, out);
}